// Round 14
// baseline (21615.742 us; speedup 1.0000x reference)
//
#include <hip/hip_runtime.h>

// GRUNet: 2-layer GRU (B=128, T=512, I=64, H=256) + ReLU + FC(256->2).
// Round 14: r7 topology with INTRA-WG TLP — NT=1024, 16 waves, 4/SIMD.
//   r13 lesson: cross-WG co-residency is not schedulable; r7's 4us of
//   latency/step is exposed at 2 waves/SIMD. Fix inside the WG:
//   - 8 groups x 32 WGs (r7 verbatim topology); NT=1024 = 16 waves =
//     (lay 2) x (rowhalf 2) x (k-quarter 4). Every wave computes all 3
//     gates over its K-quarter -> 48 weight VGPRs/thread (was 96) ->
//     fits the 128-VGPR cap of 4 waves/SIMD. __launch_bounds__(1024)
//     only (no 2nd arg — r12 trap).
//   - Partials gain kq dim: [2 lay x 4 kq][16 rows][36]; finisher sums 4.
//   - Sweep: wave = one row, lane = adjacent u64 pair (16B coalesced),
//     one ds_write_b128 unpack (r13-proven).
//   - Mantissa-tag dataflow (2 LSBs, ring 3, tag cycle 4), 3 barriers/
//     step, publish/poll timing, FC epilogue: r7 verbatim.

namespace {
constexpr int kB = 128, kT = 512, kI = 64, kH = 256, kBH = kB * kH;
constexpr int RPG = 16, NWG = 256, NT = 1024;

// activation stage: [kseg 8][row 16][32], row stride 36, kseg stride 580
constexpr int SRS = 36;
constexpr int SKS = 16 * SRS + 4;          // 580
constexpr int O_S0 = 0;                    // h0(s-1) stage
constexpr int O_S1 = O_S0 + 8 * SKS;       // h1(s-2) stage
constexpr int O_X  = O_S1 + 8 * SKS;       // [16][68] x(s)
constexpr int O_PB = O_X + RPG * 68;       // partials [8 cells][16 rows][36]
constexpr int PBN  = 8 * 16 * SRS;         // 4608
constexpr int LDSF = O_PB + PBN;           // 14976 floats = 59904 B
}

using ull = unsigned long long;
using u32 = unsigned;

__device__ __forceinline__ float sigf(float v) { return 1.0f / (1.0f + expf(-v)); }
__device__ __forceinline__ float dot4(const float4 a, const float4 b) {
  return a.x * b.x + a.y * b.y + a.z * b.z + a.w * b.w;
}
__device__ __forceinline__ float red8(float v) {   // sum over kseg lanes (bits 3..5)
  v += __shfl_xor(v, 8);
  v += __shfl_xor(v, 16);
  v += __shfl_xor(v, 32);
  return v;
}
#define F4(p) (*(const float4*)(p))
#define AL(p)    __hip_atomic_load((p), __ATOMIC_RELAXED, __HIP_MEMORY_SCOPE_AGENT)
#define AS(p, v) __hip_atomic_store((p), (v), __ATOMIC_RELAXED, __HIP_MEMORY_SCOPE_AGENT)

__global__ __launch_bounds__(NT) void gru_persistent(
    const float* __restrict__ x,
    const float* __restrict__ wih0, const float* __restrict__ whh0,
    const float* __restrict__ bih0, const float* __restrict__ bhh0,
    const float* __restrict__ wih1, const float* __restrict__ whh1,
    const float* __restrict__ bih1, const float* __restrict__ bhh1,
    const float* __restrict__ fcw, const float* __restrict__ fcb,
    u32* __restrict__ h0w,    // [3][B][H] tagged dwords
    u32* __restrict__ h1w,    // [3][B][H] tagged dwords
    float* __restrict__ out)
{
  __shared__ float lds[LDSF];

  const int bid = blockIdx.x;
  const int g   = bid >> 5;            // group 0..7
  const int wg  = bid & 31;
  const int tid = threadIdx.x;
  const int r0  = g * RPG;
  const int j0  = wg * 8;

  const int wv   = tid >> 6, lane = tid & 63;
  const int lay  = wv >> 3;            // waves 0-7: l0, 8-15: l1
  const int wl   = wv & 7;
  const int rh   = wl >> 2;            // row half
  const int kq   = (wl + (rh ? 2 : 0)) & 3;   // k-quarter, SIMD-rotated
  const int ju   = lane & 7;           // unit 0..7
  const int ks   = lane >> 3;          // local kseg 0..7 (8 floats each)
  const int jg   = j0 + ju;
  const bool doA = (lay == 1) || (kq == 0);   // A-matvec participation

  // zero partial buffer once (unwritten slots must stay 0 forever)
  for (int i = tid; i < PBN; i += NT) lds[O_PB + i] = 0.f;

  // ---- weight slices into registers (once): 12 float4 = 48 VGPR ----
  // l1: A = wih1 (vs h0), B = whh1 (vs h1). l0: A = wih0 (vs x, kq0 only),
  // B = whh0 (vs h0). K-slice = kq*64 + ks*8 (8 floats per gate per matvec).
  float4 wA[3][2], wB[3][2];
  if (lay == 0) {
    #pragma unroll
    for (int gg = 0; gg < 3; ++gg) {
      const float* wh = whh0 + (size_t)(gg * kH + jg) * kH + kq * 64 + ks * 8;
      wB[gg][0] = F4(wh); wB[gg][1] = F4(wh + 4);
      if (kq == 0) {
        const float* wi = wih0 + (size_t)(gg * kH + jg) * kI + ks * 8;
        wA[gg][0] = F4(wi); wA[gg][1] = F4(wi + 4);
      } else {
        wA[gg][0] = float4{0, 0, 0, 0}; wA[gg][1] = float4{0, 0, 0, 0};
      }
    }
  } else {
    #pragma unroll
    for (int gg = 0; gg < 3; ++gg) {
      const float* wi = wih1 + (size_t)(gg * kH + jg) * kH + kq * 64 + ks * 8;
      const float* wh = whh1 + (size_t)(gg * kH + jg) * kH + kq * 64 + ks * 8;
      wA[gg][0] = F4(wi); wA[gg][1] = F4(wi + 4);
      wB[gg][0] = F4(wh); wB[gg][1] = F4(wh + 4);
    }
  }

  // ---- finisher constants (tid < 256: layf = tid>>7, 16 rows x 8 units) ----
  float fb_r = 0.f, fb_z = 0.f, fn_i = 0.f, fn_h = 0.f;
  if (tid < 256) {
    const int layf = tid >> 7, uf = tid & 7, jf = j0 + uf;
    const float* bi = layf ? bih1 : bih0;
    const float* bh = layf ? bhh1 : bhh0;
    fb_r = bi[jf] + bh[jf];
    fb_z = bi[kH + jf] + bh[kH + jf];
    fn_i = bi[2 * kH + jf];
    fn_h = bh[2 * kH + jf];
  }

  // sweep: wave = one row (16 waves = 16 rows); lane owns u64 pair
  const int SRO = wv;                  // staged row 0..15
  const int SK2 = 2 * (tid & 63);      // even u64 col -> 16B-aligned pair

  __syncthreads();

  // ---- 513 steps: sweep -> sync -> dot -> sync -> finish -> sync ----
  for (int s = 0; s <= kT; ++s) {
    const int slot0 = (s + 2) % 3;           // h0(s-1)
    const int slot1 = (s + 1) % 3;           // h1(s-2)
    const u32 e0 = (u32)(s & 3);
    const u32 e1 = (u32)((s - 1) & 3);

    // x(s) pre-issue (plain loads)
    float4 xv = {};
    if (s < kT && tid < 256) {
      const int ro = tid >> 4, c4 = (tid & 15) * 4;
      xv = F4(x + (size_t)(r0 + ro) * kT * kI + (size_t)s * kI + c4);
    }

    // sweep-poll h data (pre-issue, retry whole sweep on tag miss)
    const ull* A0 = (const ull*)(h0w + (size_t)slot0 * kBH +
                                 (size_t)(r0 + SRO) * kH) + SK2;
    ull v00 = AL(A0), v01 = AL(A0 + 1);
    const ull* A1 = nullptr;
    ull v10 = 0, v11 = 0;
    if (s >= 1) {
      A1 = (const ull*)(h1w + (size_t)slot1 * kBH +
                        (size_t)(r0 + SRO) * kH) + SK2;
      v10 = AL(A1); v11 = AL(A1 + 1);
    }
    for (;;) {
      u32 bad = ((u32)v00 ^ e0) | ((u32)(v00 >> 32) ^ e0) |
                ((u32)v01 ^ e0) | ((u32)(v01 >> 32) ^ e0);
      if (s >= 1)
        bad |= ((u32)v10 ^ e1) | ((u32)(v10 >> 32) ^ e1) |
               ((u32)v11 ^ e1) | ((u32)(v11 >> 32) ^ e1);
      if (!(bad & 3u)) break;
      __builtin_amdgcn_s_sleep(1);
      v00 = AL(A0); v01 = AL(A0 + 1);
      if (s >= 1) { v10 = AL(A1); v11 = AL(A1 + 1); }
    }
    // unpack: one b128 write per buffer
    {
      const int ksg = SK2 >> 4, off = (SK2 * 2) & 31;
      float4 f0;
      f0.x = __uint_as_float((u32)v00); f0.y = __uint_as_float((u32)(v00 >> 32));
      f0.z = __uint_as_float((u32)v01); f0.w = __uint_as_float((u32)(v01 >> 32));
      *(float4*)(lds + O_S0 + ksg * SKS + SRO * SRS + off) = f0;
      if (s >= 1) {
        float4 f1;
        f1.x = __uint_as_float((u32)v10); f1.y = __uint_as_float((u32)(v10 >> 32));
        f1.z = __uint_as_float((u32)v11); f1.w = __uint_as_float((u32)(v11 >> 32));
        *(float4*)(lds + O_S1 + ksg * SKS + SRO * SRS + off) = f1;
      }
    }
    if (s < kT && tid < 256) {
      const int ro = tid >> 4, c4 = (tid & 15) * 4;
      *(float4*)(lds + O_X + ro * 68 + c4) = xv;
    }
    __syncthreads();

    // dot phase: all 3 gates over this wave's K-quarter, 8 rows
    const bool wact = lay ? (s >= 1) : (s < kT);
    if (wact) {
      const int koff = (2 * kq + (ks >> 2)) * SKS + (ks & 3) * 8;
      float prr[8], pzz[8], pni[8], pnh[8];
      #pragma unroll
      for (int r = 0; r < 8; ++r) {
        const int ro = rh * 8 + r;
        float pr = 0.f, pz = 0.f, xi = 0.f, xh = 0.f;
        const float* aB = lds + (lay ? O_S1 : O_S0) + koff + ro * SRS;
        const float4 b0 = F4(aB), b1 = F4(aB + 4);
        pr += dot4(b0, wB[0][0]) + dot4(b1, wB[0][1]);
        pz += dot4(b0, wB[1][0]) + dot4(b1, wB[1][1]);
        xh += dot4(b0, wB[2][0]) + dot4(b1, wB[2][1]);
        if (doA) {
          const float* aA = lay ? (lds + O_S0 + koff + ro * SRS)
                                : (lds + O_X + ro * 68 + ks * 8);
          const float4 a0 = F4(aA), a1 = F4(aA + 4);
          pr += dot4(a0, wA[0][0]) + dot4(a1, wA[0][1]);
          pz += dot4(a0, wA[1][0]) + dot4(a1, wA[1][1]);
          xi += dot4(a0, wA[2][0]) + dot4(a1, wA[2][1]);
        }
        prr[r] = pr; pzz[r] = pz; pni[r] = xi; pnh[r] = xh;
      }
      #pragma unroll
      for (int r = 0; r < 8; ++r) { prr[r] = red8(prr[r]); pzz[r] = red8(pzz[r]); }
      #pragma unroll
      for (int r = 0; r < 8; ++r) pnh[r] = red8(pnh[r]);
      if (doA) {
        #pragma unroll
        for (int r = 0; r < 8; ++r) pni[r] = red8(pni[r]);
      }
      if (ks == 0) {
        #pragma unroll
        for (int r = 0; r < 8; ++r) {
          float* pb = lds + O_PB + ((lay * 4 + kq) * 16 + rh * 8 + r) * SRS + ju;
          pb[0] = prr[r]; pb[8] = pzz[r]; pb[24] = pnh[r];
          if (doA) pb[16] = pni[r];
        }
      }
    }
    __syncthreads();

    // finish: gates + tagged publish (256 threads), summing 4 kq cells
    if (tid < 256) {
      const int layf = tid >> 7;
      const bool act = layf ? (s >= 1) : (s < kT);
      if (act) {
        const int rof = (tid >> 3) & 15, uf = tid & 7, jf = j0 + uf;
        const float* pbase = lds + O_PB + (layf * 4 * 16 + rof) * SRS + uf;
        float sr = fb_r, sz = fb_z, si = fn_i, sh = fn_h;
        #pragma unroll
        for (int q = 0; q < 4; ++q) {
          const float* pp = pbase + q * 16 * SRS;
          sr += pp[0]; sz += pp[8]; si += pp[16]; sh += pp[24];
        }
        const float rr = sigf(sr);
        const float zz = sigf(sz);
        const float nn = tanhf(si + rr * sh);
        const float hp = lds[(layf ? O_S1 : O_S0) +
                             (jf >> 5) * SKS + rof * SRS + (jf & 31)];
        const float hv = (1.f - zz) * nn + zz * hp;
        // h0(s) -> slot s%3, tag (s+1)&3; h1(s-1) -> slot (s-1)%3, tag s&3
        const int slot = layf ? ((s - 1) % 3) : (s % 3);
        const u32 tag = layf ? (u32)(s & 3) : (u32)((s + 1) & 3);
        const u32 bits = (__float_as_uint(hv) & ~3u) | tag;
        u32* hw = (layf ? h1w : h0w) + (size_t)slot * kBH +
                  (size_t)(r0 + rof) * kH + jf;
        AS(hw, bits);
      }
    }
    __syncthreads();
  }

  // ---- FC epilogue: group's WG0; h1(T-1) slot (kT-1)%3=1, tag kT&3=0 ----
  if (wg == 0 && tid < 256) {
    const int rv = tid >> 4, o = (tid >> 3) & 1, kseg = tid & 7;
    const u32* hf = h1w + (size_t)((kT - 1) % 3) * kBH + (size_t)(r0 + rv) * kH;
    const float* wfc = fcw + (size_t)o * kH;
    float acc = 0.f;
    for (int k = kseg * 32; k < kseg * 32 + 32; ++k) {
      u32 b;
      do {
        b = AL(hf + k);
      } while ((b & 3u) != (u32)(kT & 3));
      acc += fmaxf(__uint_as_float(b), 0.f) * wfc[k];
    }
    acc += __shfl_xor(acc, 1);
    acc += __shfl_xor(acc, 2);
    acc += __shfl_xor(acc, 4);
    if (kseg == 0) out[(r0 + rv) * 2 + o] = acc + fcb[o];
  }
}

extern "C" void kernel_launch(void* const* d_in, const int* in_sizes, int n_in,
                              void* d_out, int out_size, void* d_ws, size_t ws_size,
                              hipStream_t stream) {
  const float* x    = (const float*)d_in[0];
  const float* wih0 = (const float*)d_in[1];
  const float* whh0 = (const float*)d_in[2];
  const float* bih0 = (const float*)d_in[3];
  const float* bhh0 = (const float*)d_in[4];
  const float* wih1 = (const float*)d_in[5];
  const float* whh1 = (const float*)d_in[6];
  const float* bih1 = (const float*)d_in[7];
  const float* bhh1 = (const float*)d_in[8];
  const float* fcw  = (const float*)d_in[9];
  const float* fcb  = (const float*)d_in[10];

  u32* h0w = (u32*)d_ws;                 // [3][B][H] tagged
  u32* h1w = h0w + 3 * kBH;              // [3][B][H] tagged
  float* out = (float*)d_out;

  // zero tagged h buffers (tag 0 == t=-1 state) every call
  hipMemsetAsync(d_ws, 0, (size_t)(6 * kBH) * sizeof(u32), stream);

  gru_persistent<<<NWG, NT, 0, stream>>>(
      x, wih0, whh0, bih0, bhh0, wih1, whh1, bih1, bhh1,
      fcw, fcb, h0w, h1w, out);
}